// Round 4
// baseline (7470.768 us; speedup 1.0000x reference)
//
#include <hip/hip_runtime.h>

// ---- problem constants ----
#define T_SEQ 512
#define NBATCH 64
#define NIN 512
#define NHID 1024
#define NOUT 512
#define KTOT (NIN + NHID)   // 1536
#define NBLK_R 256          // recurrent blocks: (2 batch-halves) x (128 unit-groups)
#define NSUB 16             // split arrival counters

typedef __bf16 bf16;
typedef unsigned long long u64;
typedef __attribute__((ext_vector_type(8))) __bf16 bf16x8;
typedef __attribute__((ext_vector_type(4))) float f32x4;

// ---- workspace layout (bytes) ----
// xb   : [T][64][512] bf16                         33,554,432
// Wcat : [4096][1536] bf16                         12,582,912
// Woutb: [512][1024] bf16                           1,048,576
// hs   : [T+1][2 bh][128 kgrp][32 b][8 u] bf16     67,239,936
// cnt  : [16 sub][513 t] u32                            32,832
#define OFF_XB   0ull
#define OFF_W    33554432ull
#define OFF_WOUT 46137344ull
#define OFF_H    47185920ull
#define OFF_CNT  114425856ull
#define WS_NEEDED (OFF_CNT + (size_t)NSUB * 513 * 4)

#define MFMA16(a, b, c) __builtin_amdgcn_mfma_f32_16x16x32_bf16(a, b, c, 0, 0, 0)

// ---------------- prep kernels ----------------

__global__ void pack_weights(const float* __restrict__ Wxf, const float* __restrict__ Whf,
                             const float* __restrict__ Wxi, const float* __restrict__ Whi,
                             const float* __restrict__ Wxc, const float* __restrict__ Whc,
                             const float* __restrict__ Wxo, const float* __restrict__ Who,
                             const float* __restrict__ Wout,
                             bf16* __restrict__ Wcat, bf16* __restrict__ Woutb) {
    int r = blockIdx.x;
    if (r < 4 * NHID) {
        int g = r >> 10, j = r & (NHID - 1);
        const float* Wx = (g == 0 ? Wxf : g == 1 ? Wxi : g == 2 ? Wxc : Wxo);
        const float* Wh = (g == 0 ? Whf : g == 1 ? Whi : g == 2 ? Whc : Who);
        for (int k = threadIdx.x; k < KTOT; k += blockDim.x) {
            float v = (k < NIN) ? Wx[(size_t)j * NIN + k] : Wh[(size_t)j * NHID + (k - NIN)];
            Wcat[(size_t)r * KTOT + k] = (bf16)v;
        }
    } else {
        int o = r - 4 * NHID;
        for (int k = threadIdx.x; k < NHID; k += blockDim.x)
            Woutb[(size_t)o * NHID + k] = (bf16)Wout[(size_t)o * NHID + k];
    }
}

// x[b][t][i] fp32 -> xb[t][b][i] bf16
__global__ void conv_x(const float* __restrict__ x, bf16* __restrict__ xb) {
    int bt = blockIdx.x;
    int b = bt >> 9, t = bt & (T_SEQ - 1);
    const float* src = x + ((size_t)b * T_SEQ + t) * NIN;
    bf16* dst = xb + ((size_t)t * NBATCH + b) * NIN;
    for (int i = threadIdx.x; i < NIN; i += blockDim.x)
        dst[i] = (bf16)src[i];
}

__global__ void zero_init(unsigned int* __restrict__ cnt, unsigned int* __restrict__ h0) {
    int i = blockIdx.x * blockDim.x + threadIdx.x;
    if (i < NSUB * (T_SEQ + 1)) cnt[i] = 0;
    if (i < NBATCH * NHID / 2) h0[i] = 0;   // h slot 0 (both bh planes) = 64K bf16
}

// ---------------- recurrent persistent kernel ----------------
// 256 blocks x 256 threads (1 block/CU). Block (bh = blk>>7, ug = blk&127) owns
// batches bh*32..+31 x hidden units ug*8..+7 (32 gate cols: [f i c o] x 8).
// W slice (32 rows x 1536) lives in VGPRs: wave w holds k-steps (w + 4i)
// (i=0..11, 32 k each); i<4 is the x part (k<512), i>=4 the h part.
// Per step: 4 waves compute partial 32x32 g, reduce in LDS, 256 threads do the
// elementwise update (c in 1 f32/thread), h written as agent-scope u64 stores
// to a block-exclusive 512B region, split arrival counters, and readers use
// an agent acquire fence after the wait (remote L2s are never invalidated by
// stores on gfx950, so the fence is mandatory against prefetched stale lines).
__launch_bounds__(256, 1)
__global__ void lstm_rec(const bf16* __restrict__ xb, const bf16* __restrict__ Wcat,
                         const float* __restrict__ bhf, const float* __restrict__ bhi,
                         const float* __restrict__ bhc, const float* __restrict__ bho,
                         bf16* __restrict__ hs, unsigned int* __restrict__ cnt) {
    const int blk = blockIdx.x;
    const int bh = blk >> 7;        // batch half
    const int ug = blk & 127;       // unit group
    const int tid = threadIdx.x;
    const int w = tid >> 6;         // wave = k-interleave index
    const int l = tid & 63;
    const int col = l & 15;
    const int khalf = l >> 4;

    __shared__ float part[4][32][32];      // 16 KB partial sums
    __shared__ u64 hstage64[64];           // 512 B h staging

    // ---- load W fragments into registers (time-invariant) ----
    bf16x8 br[2][12];
#pragma unroll
    for (int nt = 0; nt < 2; ++nt) {
        int n = nt * 16 + col, g = n >> 3, jj = n & 7;
        const bf16* wrow = Wcat + (size_t)(g * NHID + ug * 8 + jj) * KTOT + khalf * 8;
#pragma unroll
        for (int i = 0; i < 12; ++i)
            br[nt][i] = *(const bf16x8*)(wrow + (w + i * 4) * 32);
    }

    // ---- elementwise-role constants ----
    const int eb = tid >> 3, ej = tid & 7;
    const float bias0 = bhf[ug * 8 + ej];
    const float bias1 = bhi[ug * 8 + ej];
    const float bias2 = bhc[ug * 8 + ej];
    const float bias3 = bho[ug * 8 + ej];
    float c_state = 0.f;

    const int gb0 = bh * 32 + col;  // global batch for A-frag row, m-tile 0
    __syncthreads();

    for (int t = 0; t < T_SEQ; ++t) {
        f32x4 acc00 = {0.f, 0.f, 0.f, 0.f}, acc01 = acc00, acc10 = acc00, acc11 = acc00;

        // ---- x phase (h-independent: overlaps other blocks finishing step t-1) ----
        const bf16* xrow0 = xb + ((size_t)t * NBATCH + gb0) * NIN + khalf * 8;
        const bf16* xrow1 = xrow0 + 16 * NIN;
#pragma unroll
        for (int i = 0; i < 4; ++i) {
            bf16x8 a0 = *(const bf16x8*)(xrow0 + (w + i * 4) * 32);
            bf16x8 a1 = *(const bf16x8*)(xrow1 + (w + i * 4) * 32);
            acc00 = MFMA16(a0, br[0][i], acc00);
            acc01 = MFMA16(a0, br[1][i], acc01);
            acc10 = MFMA16(a1, br[0][i], acc10);
            acc11 = MFMA16(a1, br[1][i], acc11);
        }

        // ---- wait for h_t arrival ----
        if (t > 0) {
            if (tid == 0) {
                unsigned s = 0;
                while (s < (unsigned)NBLK_R) {
                    s = 0;
#pragma unroll
                    for (int k2 = 0; k2 < NSUB; ++k2)
                        s += __hip_atomic_load(&cnt[k2 * (T_SEQ + 1) + t],
                                               __ATOMIC_RELAXED, __HIP_MEMORY_SCOPE_AGENT);
                }
            }
            __syncthreads();
            __builtin_amdgcn_fence(__ATOMIC_ACQUIRE, "agent");  // inv stale L1/L2
        }

        // ---- h phase ----
        const bf16* hpl = hs + ((size_t)t * 2 + bh) * 32768;
#pragma unroll
        for (int i = 4; i < 12; ++i) {
            int kg = (w + i * 4) * 4 + khalf - 64;   // 0..127
            bf16x8 a0 = *(const bf16x8*)(hpl + (kg * 32 + col) * 8);
            bf16x8 a1 = *(const bf16x8*)(hpl + (kg * 32 + 16 + col) * 8);
            acc00 = MFMA16(a0, br[0][i], acc00);
            acc01 = MFMA16(a0, br[1][i], acc01);
            acc10 = MFMA16(a1, br[0][i], acc10);
            acc11 = MFMA16(a1, br[1][i], acc11);
        }

        // ---- partial sums to LDS (D layout: row = khalf*4+r, col = l&15) ----
#pragma unroll
        for (int r = 0; r < 4; ++r) {
            int brow = khalf * 4 + r;
            part[w][brow][col]           = acc00[r];
            part[w][brow][16 + col]      = acc01[r];
            part[w][16 + brow][col]      = acc10[r];
            part[w][16 + brow][16 + col] = acc11[r];
        }
        __syncthreads();

        // ---- elementwise gate update: thread = (batch eb, unit ej) ----
        float gf = part[0][eb][ej]      + part[1][eb][ej]      + part[2][eb][ej]      + part[3][eb][ej]      + bias0;
        float gi = part[0][eb][8 + ej]  + part[1][eb][8 + ej]  + part[2][eb][8 + ej]  + part[3][eb][8 + ej]  + bias1;
        float gc = part[0][eb][16 + ej] + part[1][eb][16 + ej] + part[2][eb][16 + ej] + part[3][eb][16 + ej] + bias2;
        float go = part[0][eb][24 + ej] + part[1][eb][24 + ej] + part[2][eb][24 + ej] + part[3][eb][24 + ej] + bias3;
        float f  = 1.f / (1.f + __expf(-gf));
        float ii = 1.f / (1.f + __expf(-gi));
        float ch = 1.f - 2.f / (__expf(2.f * gc) + 1.f);     // tanh
        float o  = 1.f / (1.f + __expf(-go));
        c_state = f * c_state + ii * ch;
        float th = 1.f - 2.f / (__expf(2.f * c_state) + 1.f);
        ((bf16*)hstage64)[tid] = (bf16)(o * th);
        __syncthreads();

        // ---- publish h: block-exclusive 512B region, agent-coherent stores ----
        if (tid < 64) {
            u64* dst = (u64*)(hs + ((size_t)(t + 1) * 2 + bh) * 32768) + ug * 64 + tid;
            __hip_atomic_store(dst, hstage64[tid], __ATOMIC_RELAXED, __HIP_MEMORY_SCOPE_AGENT);
        }
        __syncthreads();   // drains vmcnt: all 64 stores globally visible
        if (tid == 0)
            __hip_atomic_fetch_add(&cnt[(blk & (NSUB - 1)) * (T_SEQ + 1) + (t + 1)], 1u,
                                   __ATOMIC_RELEASE, __HIP_MEMORY_SCOPE_AGENT);
    }
}

// ---------------- output GEMM: out = h_T @ Wout^T + bout (fp32 out!) ----------------
__launch_bounds__(256)
__global__ void out_gemm(const bf16* __restrict__ hs, const bf16* __restrict__ Woutb,
                         const float* __restrict__ bout, float* __restrict__ out) {
    int blk = blockIdx.x;           // 32 blocks x 16 output cols
    int tid = threadIdx.x;
    int w = tid >> 6, l = tid & 63, col = l & 15, khalf = l >> 4;
    int oc = blk * 16 + col;
    int bA = w * 16 + col;          // A-frag batch row
    int bhh = bA >> 5, b_in = bA & 31;
    const bf16* hpl = hs + ((size_t)T_SEQ * 2 + bhh) * 32768;
    const bf16* bp = Woutb + (size_t)oc * NHID + khalf * 8;
    f32x4 acc = {0.f, 0.f, 0.f, 0.f};
#pragma unroll
    for (int ks = 0; ks < NHID / 32; ++ks) {
        int kg = ks * 4 + khalf;
        bf16x8 a = *(const bf16x8*)(hpl + (kg * 32 + b_in) * 8);
        bf16x8 b = *(const bf16x8*)(bp + ks * 32);
        acc = MFMA16(a, b, acc);
    }
    float bo = bout[oc];
#pragma unroll
    for (int r = 0; r < 4; ++r) {
        int b = w * 16 + khalf * 4 + r;
        out[(size_t)b * NOUT + oc] = acc[r] + bo;   // fp32 store — reference output dtype
    }
}

// ---------------- launch ----------------
extern "C" void kernel_launch(void* const* d_in, const int* in_sizes, int n_in,
                              void* d_out, int out_size, void* d_ws, size_t ws_size,
                              hipStream_t stream) {
    const float* x    = (const float*)d_in[0];
    const float* Wxf  = (const float*)d_in[1];
    const float* Whf  = (const float*)d_in[2];
    const float* bhf  = (const float*)d_in[3];
    const float* Wxi  = (const float*)d_in[4];
    const float* Whi  = (const float*)d_in[5];
    const float* bhi  = (const float*)d_in[6];
    const float* Wxc  = (const float*)d_in[7];
    const float* Whc  = (const float*)d_in[8];
    const float* bhc  = (const float*)d_in[9];
    const float* Wxo  = (const float*)d_in[10];
    const float* Who  = (const float*)d_in[11];
    const float* bho  = (const float*)d_in[12];
    const float* Wout = (const float*)d_in[13];
    const float* bout = (const float*)d_in[14];

    if (ws_size < WS_NEEDED) return;

    char* ws = (char*)d_ws;
    bf16* xb    = (bf16*)(ws + OFF_XB);
    bf16* Wcat  = (bf16*)(ws + OFF_W);
    bf16* Woutb = (bf16*)(ws + OFF_WOUT);
    bf16* hs    = (bf16*)(ws + OFF_H);
    unsigned int* cnt = (unsigned int*)(ws + OFF_CNT);

    pack_weights<<<4 * NHID + NOUT, 256, 0, stream>>>(Wxf, Whf, Wxi, Whi, Wxc, Whc,
                                                      Wxo, Who, Wout, Wcat, Woutb);
    conv_x<<<T_SEQ * NBATCH, 256, 0, stream>>>(x, xb);
    zero_init<<<129, 256, 0, stream>>>(cnt, (unsigned int*)hs);
    lstm_rec<<<NBLK_R, 256, 0, stream>>>(xb, Wcat, bhf, bhi, bhc, bho, hs, cnt);
    out_gemm<<<NOUT / 16, 256, 0, stream>>>(hs, Woutb, bout, (float*)d_out);
}

// Round 5
// 3887.987 us; speedup vs baseline: 1.9215x; 1.9215x over previous
//
#include <hip/hip_runtime.h>

// ---- problem constants ----
#define T_SEQ 512
#define NBATCH 64
#define NIN 512
#define NHID 1024
#define NOUT 512
#define KTOT 1536
#define NBLK_R 256
#define NDOM 4             // independent sync domains (16 batches each)
#define UBLK 64            // unit-blocks per domain (16 hidden units each)

typedef __bf16 bf16;
typedef unsigned long long u64;
typedef __attribute__((ext_vector_type(8))) __bf16 bf16x8;
typedef __attribute__((ext_vector_type(4))) float f32x4;

// ---- workspace layout (bytes) ----
// xb   : [T][64][512] bf16                          33,554,432
// Wcat : [4096][1536] bf16                          12,582,912
// Woutb: [512][1024] bf16                            1,048,576
// hs   : [T+1][4 dom][64 ug][16 b][16 u] bf16       67,239,936
// flags: [T+1][4 dom][64 ub] u32                       525,312
#define OFF_XB   0ull
#define OFF_W    33554432ull
#define OFF_WOUT 46137344ull
#define OFF_H    47185920ull
#define OFF_FLAG 114425856ull
#define WS_NEEDED (OFF_FLAG + 513ull * NDOM * UBLK * 4)

#define MFMA16(a, b, c) __builtin_amdgcn_mfma_f32_16x16x32_bf16(a, b, c, 0, 0, 0)

// ---------------- prep kernels ----------------

__global__ void pack_weights(const float* __restrict__ Wxf, const float* __restrict__ Whf,
                             const float* __restrict__ Wxi, const float* __restrict__ Whi,
                             const float* __restrict__ Wxc, const float* __restrict__ Whc,
                             const float* __restrict__ Wxo, const float* __restrict__ Who,
                             const float* __restrict__ Wout,
                             bf16* __restrict__ Wcat, bf16* __restrict__ Woutb) {
    int r = blockIdx.x;
    if (r < 4 * NHID) {
        int g = r >> 10, j = r & (NHID - 1);
        const float* Wx = (g == 0 ? Wxf : g == 1 ? Wxi : g == 2 ? Wxc : Wxo);
        const float* Wh = (g == 0 ? Whf : g == 1 ? Whi : g == 2 ? Whc : Who);
        for (int k = threadIdx.x; k < KTOT; k += blockDim.x) {
            float v = (k < NIN) ? Wx[(size_t)j * NIN + k] : Wh[(size_t)j * NHID + (k - NIN)];
            Wcat[(size_t)r * KTOT + k] = (bf16)v;
        }
    } else {
        int o = r - 4 * NHID;
        for (int k = threadIdx.x; k < NHID; k += blockDim.x)
            Woutb[(size_t)o * NHID + k] = (bf16)Wout[(size_t)o * NHID + k];
    }
}

// x[b][t][i] fp32 -> xb[t][b][i] bf16
__global__ void conv_x(const float* __restrict__ x, bf16* __restrict__ xb) {
    int bt = blockIdx.x;
    int b = bt >> 9, t = bt & (T_SEQ - 1);
    const float* src = x + ((size_t)b * T_SEQ + t) * NIN;
    bf16* dst = xb + ((size_t)t * NBATCH + b) * NIN;
    for (int i = threadIdx.x; i < NIN; i += blockDim.x)
        dst[i] = (bf16)src[i];
}

__global__ void zero_init(unsigned int* __restrict__ flags, unsigned int* __restrict__ h0) {
    const int n_fl = 513 * NDOM * UBLK;          // whole flag region (poison-proof)
    const int n_h0 = NDOM * 16384 / 2;           // h slot 0 = 4 planes x 32KB
    for (int i = blockIdx.x * blockDim.x + threadIdx.x; i < n_fl; i += gridDim.x * blockDim.x)
        flags[i] = 0;
    for (int i = blockIdx.x * blockDim.x + threadIdx.x; i < n_h0; i += gridDim.x * blockDim.x)
        h0[i] = 0;
}

// ---------------- recurrent persistent kernel ----------------
// 256 blocks x 256 threads (1/CU). Block (bg = blk&3, ub = blk>>2) owns batches
// bg*16..+15 x hidden units ub*16..+15. Sync domain = 64 blocks sharing bg
// (batch-diagonal recurrence: domains never communicate). Wave = gate g.
// W rows for gate g (16 units x 1536 k) live in registers (48 bf16x8/lane).
// No per-step cache fence: h slots are fresh-address streaming writes (sc1
// write-through); no reader cache can hold a line it never read. Flags are
// per-block stores (no RMW), polled 64-wide (lane l polls unit-block l).
__launch_bounds__(256, 1)
__global__ void lstm_rec(const bf16* __restrict__ xb, const bf16* __restrict__ Wcat,
                         const float* __restrict__ bhf, const float* __restrict__ bhi,
                         const float* __restrict__ bhc, const float* __restrict__ bho,
                         bf16* __restrict__ hs, unsigned int* __restrict__ flags) {
    const int blk = blockIdx.x;
    const int bg = blk & (NDOM - 1);   // batch group / sync domain
    const int ub = blk >> 2;           // unit-block (16 units)
    const int tid = threadIdx.x;
    const int g = tid >> 6;            // wave = gate (0=f,1=i,2=c,3=o)
    const int l = tid & 63;
    const int col = l & 15;            // A: batch-in-group row, B: unit col
    const int khalf = l >> 4;

    __shared__ float part[4][16][18];  // [gate][batch][unit] padded (+2)
    __shared__ u64 hstage[64];         // [16 b][16 u] bf16 = 512 B

    // ---- W fragments (time-invariant): rows g*1024 + ub*16 + col ----
    bf16x8 br[48];
    {
        const bf16* wrow = Wcat + ((size_t)(g * NHID + ub * 16 + col)) * KTOT + khalf * 8;
#pragma unroll
        for (int s = 0; s < 48; ++s) br[s] = *(const bf16x8*)(wrow + s * 32);
    }

    // ---- elementwise roles ----
    const int eu = tid >> 4;           // unit 0..15
    const int eb = tid & 15;           // batch 0..15
    const float b_f = bhf[ub * 16 + eu];
    const float b_i = bhi[ub * 16 + eu];
    const float b_c = bhc[ub * 16 + eu];
    const float b_o = bho[ub * 16 + eu];
    float c_state = 0.f;

    const int ug0 = khalf >> 1;        // h-plane addressing statics
    const int uo = (khalf & 1) * 8;

    for (int t = 0; t < T_SEQ; ++t) {
        f32x4 acc0 = {0.f, 0.f, 0.f, 0.f}, acc1 = acc0;

        // ---- x phase (h-independent; overlaps other blocks' step t-1) ----
        const bf16* ax = xb + ((size_t)t * NBATCH + bg * 16 + col) * NIN + khalf * 8;
#pragma unroll
        for (int s = 0; s < 16; s += 2) {
            acc0 = MFMA16(*(const bf16x8*)(ax + s * 32), br[s], acc0);
            acc1 = MFMA16(*(const bf16x8*)(ax + (s + 1) * 32), br[s + 1], acc1);
        }

        // ---- wait for h_t: 64 lanes poll the domain's 64 producer flags ----
        if (t > 0) {
            if (tid < 64) {
                const unsigned int* fl = flags + ((size_t)t * NDOM + bg) * UBLK;
                while (__hip_atomic_load(&fl[l], __ATOMIC_RELAXED,
                                         __HIP_MEMORY_SCOPE_AGENT) != 1u) {}
            }
            __syncthreads();
            __builtin_amdgcn_fence(__ATOMIC_ACQUIRE, "workgroup");  // ordering only, no cache inv
        }

        // ---- h phase: plane [64 ug][16 b][16 u], fully coalesced 1KB/instr ----
        const bf16* hpl = hs + ((size_t)t * NDOM + bg) * 16384;
#pragma unroll
        for (int s = 16; s < 48; s += 2) {
            int ugA = (s - 16) * 2 + ug0;
            int ugB = (s - 15) * 2 + ug0;
            acc0 = MFMA16(*(const bf16x8*)(hpl + ugA * 256 + col * 16 + uo), br[s], acc0);
            acc1 = MFMA16(*(const bf16x8*)(hpl + ugB * 256 + col * 16 + uo), br[s + 1], acc1);
        }

        // ---- gate pre-activations to LDS (D: row=khalf*4+r, col=l&15) ----
#pragma unroll
        for (int r = 0; r < 4; ++r)
            part[g][khalf * 4 + r][col] = acc0[r] + acc1[r];
        __syncthreads();

        // ---- elementwise update: thread (eu, eb) ----
        float gf = part[0][eb][eu] + b_f;
        float gi = part[1][eb][eu] + b_i;
        float gc = part[2][eb][eu] + b_c;
        float go = part[3][eb][eu] + b_o;
        float f  = 1.f / (1.f + __expf(-gf));
        float ii = 1.f / (1.f + __expf(-gi));
        float ch = 1.f - 2.f / (__expf(2.f * gc) + 1.f);   // tanh
        float o  = 1.f / (1.f + __expf(-go));
        c_state = f * c_state + ii * ch;
        float th = 1.f - 2.f / (__expf(2.f * c_state) + 1.f);
        ((bf16*)hstage)[eb * 16 + eu] = (bf16)(o * th);
        __syncthreads();

        // ---- publish h chunk (512B, block-exclusive lines, sc1 write-through) ----
        if (tid < 64) {
            u64* dst = (u64*)(hs + ((size_t)(t + 1) * NDOM + bg) * 16384) + ub * 64 + tid;
            __hip_atomic_store(dst, hstage[tid], __ATOMIC_RELAXED, __HIP_MEMORY_SCOPE_AGENT);
        }
        __syncthreads();   // compiler drains vmcnt before barrier -> h visible
        if (tid == 0)
            __hip_atomic_store(&flags[((size_t)(t + 1) * NDOM + bg) * UBLK + ub], 1u,
                               __ATOMIC_RELEASE, __HIP_MEMORY_SCOPE_AGENT);
    }
}

// ---------------- output GEMM: out = h_T @ Wout^T + bout (fp32 out) ----------------
__launch_bounds__(256)
__global__ void out_gemm(const bf16* __restrict__ hs, const bf16* __restrict__ Woutb,
                         const float* __restrict__ bout, float* __restrict__ out) {
    int blk = blockIdx.x;              // 32 blocks x 16 output cols
    int tid = threadIdx.x;
    int w = tid >> 6, l = tid & 63, col = l & 15, khalf = l >> 4;
    int oc = blk * 16 + col;
    const bf16* hpl = hs + ((size_t)T_SEQ * NDOM + w) * 16384;   // bg = wave
    const bf16* bp = Woutb + (size_t)oc * NHID + khalf * 8;
    const int ug0 = khalf >> 1, uo = (khalf & 1) * 8;
    f32x4 acc = {0.f, 0.f, 0.f, 0.f};
#pragma unroll
    for (int ks = 0; ks < 32; ++ks) {
        bf16x8 a = *(const bf16x8*)(hpl + (ks * 2 + ug0) * 256 + col * 16 + uo);
        bf16x8 b = *(const bf16x8*)(bp + ks * 32);
        acc = MFMA16(a, b, acc);
    }
    float bo = bout[oc];
#pragma unroll
    for (int r = 0; r < 4; ++r) {
        int b = w * 16 + khalf * 4 + r;
        out[(size_t)b * NOUT + oc] = acc[r] + bo;
    }
}

// ---------------- launch ----------------
extern "C" void kernel_launch(void* const* d_in, const int* in_sizes, int n_in,
                              void* d_out, int out_size, void* d_ws, size_t ws_size,
                              hipStream_t stream) {
    const float* x    = (const float*)d_in[0];
    const float* Wxf  = (const float*)d_in[1];
    const float* Whf  = (const float*)d_in[2];
    const float* bhf  = (const float*)d_in[3];
    const float* Wxi  = (const float*)d_in[4];
    const float* Whi  = (const float*)d_in[5];
    const float* bhi  = (const float*)d_in[6];
    const float* Wxc  = (const float*)d_in[7];
    const float* Whc  = (const float*)d_in[8];
    const float* bhc  = (const float*)d_in[9];
    const float* Wxo  = (const float*)d_in[10];
    const float* Who  = (const float*)d_in[11];
    const float* bho  = (const float*)d_in[12];
    const float* Wout = (const float*)d_in[13];
    const float* bout = (const float*)d_in[14];

    if (ws_size < WS_NEEDED) return;

    char* ws = (char*)d_ws;
    bf16* xb    = (bf16*)(ws + OFF_XB);
    bf16* Wcat  = (bf16*)(ws + OFF_W);
    bf16* Woutb = (bf16*)(ws + OFF_WOUT);
    bf16* hs    = (bf16*)(ws + OFF_H);
    unsigned int* flags = (unsigned int*)(ws + OFF_FLAG);

    pack_weights<<<4 * NHID + NOUT, 256, 0, stream>>>(Wxf, Whf, Wxi, Whi, Wxc, Whc,
                                                      Wxo, Who, Wout, Wcat, Woutb);
    conv_x<<<T_SEQ * NBATCH, 256, 0, stream>>>(x, xb);
    zero_init<<<256, 256, 0, stream>>>(flags, (unsigned int*)hs);
    lstm_rec<<<NBLK_R, 256, 0, stream>>>(xb, Wcat, bhf, bhi, bhc, bho, hs, flags);
    out_gemm<<<NOUT / 16, 256, 0, stream>>>(hs, Woutb, bout, (float*)d_out);
}

// Round 6
// 3583.484 us; speedup vs baseline: 2.0848x; 1.0850x over previous
//
#include <hip/hip_runtime.h>

// ---- problem constants ----
#define T_SEQ 512
#define NBATCH 64
#define NIN 512
#define NHID 1024
#define NOUT 512
#define KTOT 1536
#define NBLK_R 256
#define NDOM 4             // sync domains (16 batches each)
#define UBLK 64            // unit-blocks per domain (16 hidden units each)

typedef __bf16 bf16;
typedef unsigned long long u64;
typedef __attribute__((ext_vector_type(8))) __bf16 bf16x8;
typedef __attribute__((ext_vector_type(4))) float f32x4;

// ---- workspace layout (bytes) ----
// xb   : [T][4 bg][32 kg][16 b][16 k] bf16 (16KB per (t,bg))   33,554,432
// Wcat : [4096][1536] bf16                                     12,582,912
// Woutb: [512][1024] bf16                                       1,048,576
// hs   : [T+1][4 bg][64 ug][16 b][16 u] bf16 (32KB per (t,bg)) 67,239,936
// flags: [T+1][4 bg][64 ub] u32                                   525,312
#define OFF_XB   0ull
#define OFF_W    33554432ull
#define OFF_WOUT 46137344ull
#define OFF_H    47185920ull
#define OFF_FLAG 114425856ull
#define WS_NEEDED (OFF_FLAG + 513ull * NDOM * UBLK * 4)

#define MFMA16(a, b, c) __builtin_amdgcn_mfma_f32_16x16x32_bf16(a, b, c, 0, 0, 0)

// LDS carve (bytes)
#define XLDS0  0
#define XLDS1  16384
#define HLDS   32768
#define PART   65536          // [4 w][4 g][16 u][17 b] f32 = 17408
#define HSTAGE 82944          // [16 b][16 u] bf16 = 512
#define LDS_SZ 83456          // > 80KB -> 1 block/CU guaranteed

#define WAITVM(N) do { asm volatile("s_waitcnt vmcnt(" #N ")" ::: "memory"); \
                       __builtin_amdgcn_sched_barrier(0); } while (0)
#define WAITLG    do { asm volatile("s_waitcnt lgkmcnt(0)" ::: "memory"); \
                       __builtin_amdgcn_sched_barrier(0); } while (0)
#define BAR()     __builtin_amdgcn_s_barrier()

__device__ __forceinline__ void glds16(const void* g, void* l) {
    __builtin_amdgcn_global_load_lds(
        (const __attribute__((address_space(1))) void*)g,
        (__attribute__((address_space(3))) void*)l, 16, 0, 0);
}

// ---------------- prep kernels ----------------

__global__ void pack_weights(const float* __restrict__ Wxf, const float* __restrict__ Whf,
                             const float* __restrict__ Wxi, const float* __restrict__ Whi,
                             const float* __restrict__ Wxc, const float* __restrict__ Whc,
                             const float* __restrict__ Wxo, const float* __restrict__ Who,
                             const float* __restrict__ Wout,
                             bf16* __restrict__ Wcat, bf16* __restrict__ Woutb) {
    int r = blockIdx.x;
    if (r < 4 * NHID) {
        int g = r >> 10, j = r & (NHID - 1);
        const float* Wx = (g == 0 ? Wxf : g == 1 ? Wxi : g == 2 ? Wxc : Wxo);
        const float* Wh = (g == 0 ? Whf : g == 1 ? Whi : g == 2 ? Whc : Who);
        for (int k = threadIdx.x; k < KTOT; k += blockDim.x) {
            float v = (k < NIN) ? Wx[(size_t)j * NIN + k] : Wh[(size_t)j * NHID + (k - NIN)];
            Wcat[(size_t)r * KTOT + k] = (bf16)v;
        }
    } else {
        int o = r - 4 * NHID;
        for (int k = threadIdx.x; k < NHID; k += blockDim.x)
            Woutb[(size_t)o * NHID + k] = (bf16)Wout[(size_t)o * NHID + k];
    }
}

// x[b][t][i] fp32 -> xb[t][bg][kg][b16][k16] bf16
__global__ void conv_x(const float* __restrict__ x, bf16* __restrict__ xb) {
    int bt = blockIdx.x;
    int b = bt >> 9, t = bt & (T_SEQ - 1);
    const float* src = x + ((size_t)b * T_SEQ + t) * NIN;
    bf16* dst = xb + ((size_t)t * NDOM + (b >> 4)) * 8192 + (b & 15) * 16;
    for (int k = threadIdx.x; k < NIN; k += blockDim.x)
        dst[(k >> 4) * 256 + (k & 15)] = (bf16)src[k];
}

__global__ void zero_init(unsigned int* __restrict__ flags, unsigned int* __restrict__ h0) {
    const int n_fl = 513 * NDOM * UBLK;
    const int n_h0 = NDOM * 16384 / 2;       // h slot 0 = 4 planes x 32KB
    for (int i = blockIdx.x * blockDim.x + threadIdx.x; i < n_fl; i += gridDim.x * blockDim.x)
        flags[i] = 0;
    for (int i = blockIdx.x * blockDim.x + threadIdx.x; i < n_h0; i += gridDim.x * blockDim.x)
        h0[i] = 0;
}

// ---------------- recurrent persistent kernel ----------------
// 256 blocks x 256 threads (1/CU via 83KB LDS). Block (bg=blk&3, ub=blk>>2):
// batches bg*16..+15 x units ub*16..+15 (64 gate rows). Waves k-split mod 4:
// wave w owns ksteps {w+4i, i=0..11} (i<4: x-part, i>=4: h-part), all 4 gates.
// W (48 bf16x8/lane) in registers/AGPRs. A-tiles staged via global_load_lds
// DMA with counted vmcnt + raw barriers: h-tile (32KB, 8 issues/wave) per
// step; x-tile (16KB, 4 issues/wave) double-buffered, prefetched 1 step ahead.
// Cross-wave k-reduction in padded LDS part[]; elementwise c-update 1/thread;
// h published as agent sc1 u64 stores to block-exclusive 512B; per-block flag.
__launch_bounds__(256, 1)
__global__ void lstm_rec(const bf16* __restrict__ xb, const bf16* __restrict__ Wcat,
                         const float* __restrict__ bhf, const float* __restrict__ bhi,
                         const float* __restrict__ bhc, const float* __restrict__ bho,
                         bf16* __restrict__ hs, unsigned int* __restrict__ flags) {
    __shared__ __attribute__((aligned(128))) char smem[LDS_SZ];

    const int blk = blockIdx.x;
    const int bg = blk & (NDOM - 1);
    const int ub = blk >> 2;
    const int tid = threadIdx.x;
    const int w = tid >> 6;
    const int l = tid & 63;
    const int col = l & 15;
    const int khalf = l >> 4;

    const char* xbB = (const char*)xb;
    const char* hsB = (const char*)hs;

    // ---- W fragments (time-invariant): gate g row = g*1024 + ub*16 + col ----
    bf16x8 br0[12], br1[12], br2[12], br3[12];
#pragma unroll
    for (int i = 0; i < 12; ++i) {
        size_t ko = (size_t)(w + 4 * i) * 32 + khalf * 8;
        br0[i] = *(const bf16x8*)(Wcat + (size_t)(0 * NHID + ub * 16 + col) * KTOT + ko);
        br1[i] = *(const bf16x8*)(Wcat + (size_t)(1 * NHID + ub * 16 + col) * KTOT + ko);
        br2[i] = *(const bf16x8*)(Wcat + (size_t)(2 * NHID + ub * 16 + col) * KTOT + ko);
        br3[i] = *(const bf16x8*)(Wcat + (size_t)(3 * NHID + ub * 16 + col) * KTOT + ko);
    }

    // ---- elementwise roles: thread = (batch eb, unit eu) ----
    const int eb = tid & 15, eu = tid >> 4;
    const float b_f = bhf[ub * 16 + eu];
    const float b_i = bhi[ub * 16 + eu];
    const float b_c = bhc[ub * 16 + eu];
    const float b_o = bho[ub * 16 + eu];
    float c_state = 0.f;

    // A-frag LDS byte offsets (within a tile): chunk(kg)*512 + col*32 + (khalf&1)*16
    const int a_lane = col * 32 + (khalf & 1) * 16;
    const int kh2 = khalf >> 1;

    // ---- prologue: DMA x tile 0 into buf0 ----
    {
        const char* xt0 = xbB + (size_t)bg * 16384;
#pragma unroll
        for (int j = 0; j < 4; ++j)
            glds16(xt0 + (w * 4 + j) * 1024 + l * 16, smem + XLDS0 + (w * 4 + j) * 1024);
        WAITVM(0);
        BAR();
    }

    for (int t = 0; t < T_SEQ; ++t) {
        // ---- B1: wait for h_t (wave 0 polls the domain's 64 producer flags) ----
        if (t > 0 && tid < 64) {
            const unsigned int* fl = flags + ((size_t)t * NDOM + bg) * UBLK;
            while (__hip_atomic_load(&fl[l], __ATOMIC_RELAXED,
                                     __HIP_MEMORY_SCOPE_AGENT) != 1u) {}
        }
        BAR();

        // ---- D: issue h_t DMA (8 chunks/wave, 32KB tile) ----
        const char* hplB = hsB + ((size_t)t * NDOM + bg) * 32768;
#pragma unroll
        for (int j = 0; j < 8; ++j)
            glds16(hplB + (w * 8 + j) * 1024 + l * 16, smem + HLDS + (w * 8 + j) * 1024);
        WAITVM(8);          // x_t residue (older) drained; h in flight
        BAR();              // B1b: x_t visible to all waves

        // ---- x-phase (overlaps h DMA): ks = w+4i, i=0..3 ----
        f32x4 acc0 = {0.f, 0.f, 0.f, 0.f}, acc1 = acc0, acc2 = acc0, acc3 = acc0;
        const char* xcur = smem + ((t & 1) ? XLDS1 : XLDS0);
#pragma unroll
        for (int i = 0; i < 4; ++i) {
            int ks = w + 4 * i;
            bf16x8 a = *(const bf16x8*)(xcur + (2 * ks + kh2) * 512 + a_lane);
            acc0 = MFMA16(a, br0[i], acc0);
            acc1 = MFMA16(a, br1[i], acc1);
            acc2 = MFMA16(a, br2[i], acc2);
            acc3 = MFMA16(a, br3[i], acc3);
        }

        // ---- issue x_{t+1} DMA into other buffer (clamped at the tail) ----
        {
            int tn = (t + 1 < T_SEQ) ? t + 1 : T_SEQ - 1;
            const char* xnB = xbB + ((size_t)tn * NDOM + bg) * 16384;
            char* xnx = smem + ((t & 1) ? XLDS0 : XLDS1);
#pragma unroll
            for (int j = 0; j < 4; ++j)
                glds16(xnB + (w * 4 + j) * 1024 + l * 16, xnx + (w * 4 + j) * 1024);
        }
        WAITVM(4);          // h_t done; only x_{t+1} (4) in flight
        BAR();              // B2: h tile visible to all waves

        // ---- h-phase: ks = w+4i, i=4..11 ----
#pragma unroll
        for (int i = 4; i < 12; ++i) {
            int ks = w + 4 * i;
            bf16x8 a = *(const bf16x8*)(smem + HLDS + (2 * (ks - 16) + kh2) * 512 + a_lane);
            acc0 = MFMA16(a, br0[i], acc0);
            acc1 = MFMA16(a, br1[i], acc1);
            acc2 = MFMA16(a, br2[i], acc2);
            acc3 = MFMA16(a, br3[i], acc3);
        }

        // ---- partial sums to LDS: part[w][g][u=col][b17 = khalf*4+r] ----
        {
            char* pw = smem + PART + ((w * 4 * 16 + col) * 17 + khalf * 4) * 4;
            *(f32x4*)(pw + (0 * 16 * 17) * 4) = acc0;
            *(f32x4*)(pw + (1 * 16 * 17) * 4) = acc1;
            *(f32x4*)(pw + (2 * 16 * 17) * 4) = acc2;
            *(f32x4*)(pw + (3 * 16 * 17) * 4) = acc3;
        }
        WAITLG;
        BAR();              // B3

        // ---- elementwise gate update ----
        {
            float gf = b_f, gi = b_i, gc = b_c, go = b_o;
#pragma unroll
            for (int w2 = 0; w2 < 4; ++w2) {
                const char* pb = smem + PART + (((w2 * 4) * 16 + eu) * 17 + eb) * 4;
                gf += *(const float*)(pb + (0 * 16 * 17) * 4);
                gi += *(const float*)(pb + (1 * 16 * 17) * 4);
                gc += *(const float*)(pb + (2 * 16 * 17) * 4);
                go += *(const float*)(pb + (3 * 16 * 17) * 4);
            }
            float f  = 1.f / (1.f + __expf(-gf));
            float ii = 1.f / (1.f + __expf(-gi));
            float ch = 1.f - 2.f / (__expf(2.f * gc) + 1.f);   // tanh
            float o  = 1.f / (1.f + __expf(-go));
            c_state = f * c_state + ii * ch;
            float th = 1.f - 2.f / (__expf(2.f * c_state) + 1.f);
            *(bf16*)(smem + HSTAGE + (eb * 16 + eu) * 2) = (bf16)(o * th);
        }
        WAITLG;
        BAR();              // B4

        // ---- publish h chunk (wave 0): 512B block-exclusive, sc1 write-through ----
        if (tid < 64) {
            u64 v = *(const u64*)(smem + HSTAGE + tid * 8);
            u64* dst = (u64*)(hsB + ((size_t)(t + 1) * NDOM + bg) * 32768 + ub * 512) + tid;
            __hip_atomic_store(dst, v, __ATOMIC_RELAXED, __HIP_MEMORY_SCOPE_AGENT);
            WAITVM(0);      // publish ack'd at coherent point
            if (tid == 0)
                __hip_atomic_store(&flags[((size_t)(t + 1) * NDOM + bg) * UBLK + ub], 1u,
                                   __ATOMIC_RELEASE, __HIP_MEMORY_SCOPE_AGENT);
        }
    }
}

// ---------------- output GEMM: out = h_T @ Wout^T + bout (fp32 out) ----------------
__launch_bounds__(256)
__global__ void out_gemm(const bf16* __restrict__ hs, const bf16* __restrict__ Woutb,
                         const float* __restrict__ bout, float* __restrict__ out) {
    int blk = blockIdx.x;              // 32 blocks x 16 output cols
    int tid = threadIdx.x;
    int w = tid >> 6, l = tid & 63, col = l & 15, khalf = l >> 4;
    int oc = blk * 16 + col;
    const bf16* hpl = hs + ((size_t)T_SEQ * NDOM + w) * 16384;   // bg = wave
    const bf16* bp = Woutb + (size_t)oc * NHID + khalf * 8;
    const int ug0 = khalf >> 1, uo = (khalf & 1) * 8;
    f32x4 acc = {0.f, 0.f, 0.f, 0.f};
#pragma unroll
    for (int ks = 0; ks < 32; ++ks) {
        bf16x8 a = *(const bf16x8*)(hpl + (ks * 2 + ug0) * 256 + col * 16 + uo);
        bf16x8 b = *(const bf16x8*)(bp + ks * 32);
        acc = MFMA16(a, b, acc);
    }
    float bo = bout[oc];
#pragma unroll
    for (int r = 0; r < 4; ++r) {
        int b = w * 16 + khalf * 4 + r;
        out[(size_t)b * NOUT + oc] = acc[r] + bo;
    }
}

// ---------------- launch ----------------
extern "C" void kernel_launch(void* const* d_in, const int* in_sizes, int n_in,
                              void* d_out, int out_size, void* d_ws, size_t ws_size,
                              hipStream_t stream) {
    const float* x    = (const float*)d_in[0];
    const float* Wxf  = (const float*)d_in[1];
    const float* Whf  = (const float*)d_in[2];
    const float* bhf  = (const float*)d_in[3];
    const float* Wxi  = (const float*)d_in[4];
    const float* Whi  = (const float*)d_in[5];
    const float* bhi  = (const float*)d_in[6];
    const float* Wxc  = (const float*)d_in[7];
    const float* Whc  = (const float*)d_in[8];
    const float* bhc  = (const float*)d_in[9];
    const float* Wxo  = (const float*)d_in[10];
    const float* Who  = (const float*)d_in[11];
    const float* bho  = (const float*)d_in[12];
    const float* Wout = (const float*)d_in[13];
    const float* bout = (const float*)d_in[14];

    if (ws_size < WS_NEEDED) return;

    char* ws = (char*)d_ws;
    bf16* xb    = (bf16*)(ws + OFF_XB);
    bf16* Wcat  = (bf16*)(ws + OFF_W);
    bf16* Woutb = (bf16*)(ws + OFF_WOUT);
    bf16* hs    = (bf16*)(ws + OFF_H);
    unsigned int* flags = (unsigned int*)(ws + OFF_FLAG);

    pack_weights<<<4 * NHID + NOUT, 256, 0, stream>>>(Wxf, Whf, Wxi, Whi, Wxc, Whc,
                                                      Wxo, Who, Wout, Wcat, Woutb);
    conv_x<<<T_SEQ * NBATCH, 256, 0, stream>>>(x, xb);
    zero_init<<<256, 256, 0, stream>>>(flags, (unsigned int*)hs);
    lstm_rec<<<NBLK_R, 256, 0, stream>>>(xb, Wcat, bhf, bhi, bhc, bho, hs, flags);
    out_gemm<<<NOUT / 16, 256, 0, stream>>>(hs, Woutb, bout, (float*)d_out);
}